// Round 7
// baseline (289.649 us; speedup 1.0000x reference)
//
#include <hip/hip_runtime.h>

// Encoder: 2-layer LSTM (H=16 each), x [B=16384, T=100, I=18], FP32 in/out.
// R7: wave-specialized producer/consumer. Each 16-batch tile is driven by TWO
// waves: an L1 wave (x load/convert + layer-1 recurrence) and an L2 wave
// (layer-2 recurrence + output). Handoff = packed relu(h1) B-frag, 16B/lane,
// LDS double-buffer, one __syncthreads per step. 2048 waves = 2/SIMD (vs the
// 1/SIMD structural limit of the fused form) -> two independently-stalling
// waves per SIMD fill each other's transcendental-latency gaps.
// Math identical to R6 (absmax 9.77e-4): G^T = W @ H^T so the packed
// (hi|lo<<16) h dwords ARE the next step's B-fragment; two-term bf16 splits
// on x/weights/states; gate math, biases, c in fp32.

typedef float f32x4 __attribute__((ext_vector_type(4)));
typedef __bf16 bf16x8 __attribute__((ext_vector_type(8)));
typedef unsigned int uint32x4 __attribute__((ext_vector_type(4)));

union FragU { bf16x8 v; unsigned short u[8]; unsigned int d[4]; uint32x4 q; };

#define MFMA16(A, B, C) __builtin_amdgcn_mfma_f32_16x16x32_bf16((A), (B), (C), 0, 0, 0)

static __device__ __forceinline__ unsigned short f2bf(float f) {  // RNE (weights)
  unsigned int u = __builtin_bit_cast(unsigned int, f);
  u = u + 0x7FFFu + ((u >> 16) & 1u);
  return (unsigned short)(u >> 16);
}
static __device__ __forceinline__ float bfbits2f(unsigned short h) {
  unsigned int u = ((unsigned int)h) << 16;
  return __builtin_bit_cast(float, u);
}
static __device__ __forceinline__ float sigm(float x) {
  return __builtin_amdgcn_rcpf(1.0f + __builtin_amdgcn_exp2f(x * -1.4426950408889634f));
}
static __device__ __forceinline__ float tanh_(float x) {
  return 1.0f - 2.0f * __builtin_amdgcn_rcpf(1.0f + __builtin_amdgcn_exp2f(x * 2.8853900817779268f));
}
// Trunc two-term split packed as (bf_hi | bf_lo<<16); hi+lo == v to 2^-16|v|.
static __device__ __forceinline__ unsigned int split_pack(float v) {
  unsigned int u = __builtin_bit_cast(unsigned int, v);
  float hf = __builtin_bit_cast(float, u & 0xFFFF0000u);
  unsigned int l = __builtin_bit_cast(unsigned int, v - hf);
  return (u >> 16) | (l & 0xFFFF0000u);
}
static __device__ __forceinline__ void cvt_pair(float f0, float f1,
                                                unsigned int& hd, unsigned int& ld) {
  unsigned int u0 = __builtin_bit_cast(unsigned int, f0);
  unsigned int u1 = __builtin_bit_cast(unsigned int, f1);
  unsigned int h0 = u0 & 0xFFFF0000u;
  unsigned int h1 = u1 & 0xFFFF0000u;
  hd = (u0 >> 16) | h1;
  unsigned int l0 = __builtin_bit_cast(unsigned int, f0 - __builtin_bit_cast(float, h0));
  unsigned int l1 = __builtin_bit_cast(unsigned int, f1 - __builtin_bit_cast(float, h1));
  ld = (l0 >> 16) | (l1 & 0xFFFF0000u);
}

struct RawX { float2 a, b2, c, d; };

__global__ __launch_bounds__(256, 2) void enc_kernel(
    const float* __restrict__ x,     // [16384,100,18]
    const float* __restrict__ Wih1,  // [64,18]
    const float* __restrict__ Whh1,  // [64,16]
    const float* __restrict__ bih1,  // [64]
    const float* __restrict__ bhh1,  // [64]
    const float* __restrict__ Wih2,  // [64,16]
    const float* __restrict__ Whh2,  // [64,16]
    const float* __restrict__ bih2,  // [64]
    const float* __restrict__ bhh2,  // [64]
    float* __restrict__ out)         // [16384,16]
{
  // Handoff buffers: [tile][t&1][lane] 16B each -> 4 KB/block.
  __shared__ __align__(16) uint32x4 buf[2][2][64];

  const int wv   = threadIdx.x >> 6;   // 0,1 = L1 producers; 2,3 = L2 consumers
  const int lane = threadIdx.x & 63;
  const int tile = wv & 1;
  const int b    = lane & 15;  // batch in tile (A m-row / B n-col / C col)
  const int g    = lane >> 4;  // k-group; C row-quad (units 4g..4g+3)
  const int b0   = ((int)blockIdx.x * 2 + tile) * 16;

  if (wv < 2) {
    // ======================= L1 PRODUCER WAVE =======================
    FragU A1h[4], A1l[4], A2h[4], A2l[4];
    f32x4 bias1v[4];
#pragma unroll
    for (int tn = 0; tn < 4; ++tn) {  // 0=i 1=f 2=g 3=o
      const int row = tn * 16 + b;
#pragma unroll
      for (int j = 0; j < 8; ++j) {
        const int k = 8 * g + j;
        if (k < 18) {
          const float w = Wih1[row * 18 + k];
          A1h[tn].u[j] = f2bf(w);
          A1l[tn].u[j] = f2bf(w - bfbits2f(A1h[tn].u[j]));
        } else {
          A1h[tn].u[j] = 0;
          A1l[tn].u[j] = 0;
        }
        const float w2 = Whh1[row * 16 + (k >> 1)];  // hi/lo dup along K
        A2h[tn].u[j] = f2bf(w2);
        A2l[tn].u[j] = f2bf(w2 - bfbits2f(A2h[tn].u[j]));
      }
#pragma unroll
      for (int r = 0; r < 4; ++r) {
        const int u4 = tn * 16 + 4 * g + r;
        bias1v[tn][r] = bih1[u4] + bhh1[u4];
      }
    }

    // x: lane (b,g) covers x[b0+b][t][8g..8g+7]; g==3 is all zero-pad (k>=24).
    const float* const x0 = x + (size_t)(b0 + b) * 1800 + 8 * g;
    const int adv = (g == 3) ? 0 : 18;

    auto loadraw = [&](const float* p) -> RawX {
      RawX r;
      r.a = *(const float2*)p;
      if (g < 2) {
        r.b2 = *(const float2*)(p + 2);
        r.c  = *(const float2*)(p + 4);
        r.d  = *(const float2*)(p + 6);
      } else {
        r.b2 = r.c = r.d = make_float2(0.f, 0.f);
      }
      return r;
    };
    auto cvt = [&](const RawX& rw_, FragU& hi, FragU& lo) {
      cvt_pair(rw_.a.x,  rw_.a.y,  hi.d[0], lo.d[0]);
      cvt_pair(rw_.b2.x, rw_.b2.y, hi.d[1], lo.d[1]);
      cvt_pair(rw_.c.x,  rw_.c.y,  hi.d[2], lo.d[2]);
      cvt_pair(rw_.d.x,  rw_.d.y,  hi.d[3], lo.d[3]);
    };

    RawX rw0 = loadraw(x0);
    RawX rw1 = loadraw(x0 + adv);
    RawX rw  = loadraw(x0 + 2 * adv);
    const float* xq = x0 + 3 * adv;  // next load: t=3

    FragU hb;  hb.q = (uint32x4){0u, 0u, 0u, 0u};
    float c1[4] = {0.f, 0.f, 0.f, 0.f};

    FragU xch, xcl;
    cvt(rw0, xch, xcl);  // x(0)

    f32x4 ga[4];  // gate preacts for t=0 (hb = 0)
#pragma unroll
    for (int tn = 0; tn < 4; ++tn) {
      f32x4 acc = MFMA16(A1h[tn].v, xch.v, bias1v[tn]);
      acc = MFMA16(A1l[tn].v, xch.v, acc);
      acc = MFMA16(A1h[tn].v, xcl.v, acc);
      acc = MFMA16(A2h[tn].v, hb.v, acc);
      acc = MFMA16(A2l[tn].v, hb.v, acc);
      ga[tn] = acc;
    }
    cvt(rw1, xch, xcl);  // x(1) for the loop's first post-barrier MFMAs

#pragma unroll 2
    for (int t = 0; t < 100; ++t) {
      // ew(t): ga -> h1(t) packed hi/lo; relu variant for handoff
      FragU rb;
#pragma unroll
      for (int r = 0; r < 4; ++r) {
        const float iv = sigm(ga[0][r]);
        const float fv = sigm(ga[1][r]);
        const float gv = tanh_(ga[2][r]);
        const float ov = sigm(ga[3][r]);
        const float cc = fv * c1[r] + iv * gv;
        c1[r] = cc;
        const float h = ov * tanh_(cc);
        const unsigned int pk = split_pack(h);
        hb.d[r] = pk;
        rb.d[r] = (h > 0.f) ? pk : 0u;
      }
      buf[tile][t & 1][lane] = rb.q;  // ds_write_b128
      __syncthreads();                // consumer may read buf[t&1]

      // ga(t+1) from x(t+1) (xch/xcl) and h1(t) (hb): full barrier interval
      // of MFMA latency before ew(t+1).
#pragma unroll
      for (int tn = 0; tn < 4; ++tn) {
        f32x4 acc = MFMA16(A1h[tn].v, xch.v, bias1v[tn]);
        acc = MFMA16(A1l[tn].v, xch.v, acc);
        acc = MFMA16(A1h[tn].v, xcl.v, acc);
        acc = MFMA16(A2h[tn].v, hb.v, acc);
        acc = MFMA16(A2l[tn].v, hb.v, acc);
        ga[tn] = acc;
      }
      cvt(rw, xch, xcl);                       // x(t+2)
      rw = loadraw((t <= 96) ? xq : x0);       // x(t+3), uniform guard
      xq += adv;
    }
  } else {
    // ======================= L2 CONSUMER WAVE =======================
    FragU A3h[4], A3l[4], A4h[4], A4l[4];
    f32x4 bias2v[4];
#pragma unroll
    for (int tn = 0; tn < 4; ++tn) {
      const int row = tn * 16 + b;
#pragma unroll
      for (int j = 0; j < 8; ++j) {
        const int kk = (8 * g + j) >> 1;  // hi/lo dup along K
        const float w3 = Wih2[row * 16 + kk];
        const float w4 = Whh2[row * 16 + kk];
        A3h[tn].u[j] = f2bf(w3); A3l[tn].u[j] = f2bf(w3 - bfbits2f(A3h[tn].u[j]));
        A4h[tn].u[j] = f2bf(w4); A4l[tn].u[j] = f2bf(w4 - bfbits2f(A4h[tn].u[j]));
      }
#pragma unroll
      for (int r = 0; r < 4; ++r) {
        const int u4 = tn * 16 + 4 * g + r;
        bias2v[tn][r] = bih2[u4] + bhh2[u4];
      }
    }

    FragU h2b;  h2b.q = (uint32x4){0u, 0u, 0u, 0u};
    float c2[4] = {0.f, 0.f, 0.f, 0.f};
    float h2v[4] = {0.f, 0.f, 0.f, 0.f};

#pragma unroll 2
    for (int t = 0; t < 100; ++t) {
      __syncthreads();  // buf[t&1] = relu(h1(t)) now visible
      FragU rq;  rq.q = buf[tile][t & 1][lane];

      // h2b-terms first: they issue while the ds_read is still in flight.
      f32x4 gb[4];
#pragma unroll
      for (int tn = 0; tn < 4; ++tn) {
        f32x4 acc = MFMA16(A4h[tn].v, h2b.v, bias2v[tn]);
        acc = MFMA16(A4l[tn].v, h2b.v, acc);
        acc = MFMA16(A3h[tn].v, rq.v, acc);
        acc = MFMA16(A3l[tn].v, rq.v, acc);
        gb[tn] = acc;
      }
#pragma unroll
      for (int r = 0; r < 4; ++r) {
        const float iv = sigm(gb[0][r]);
        const float fv = sigm(gb[1][r]);
        const float gv = tanh_(gb[2][r]);
        const float ov = sigm(gb[3][r]);
        const float cc = fv * c2[r] + iv * gv;
        c2[r] = cc;
        const float h = ov * tanh_(cc);
        h2v[r] = h;
        h2b.d[r] = split_pack(h);
      }
    }

    // output: relu(h2_last); lane (b,g) holds units 4g..4g+3 of batch b
    f32x4 o;
#pragma unroll
    for (int r = 0; r < 4; ++r) o[r] = fmaxf(h2v[r], 0.f);
    *(f32x4*)(out + (size_t)(b0 + b) * 16 + 4 * g) = o;
  }
}

extern "C" void kernel_launch(void* const* d_in, const int* in_sizes, int n_in,
                              void* d_out, int out_size, void* d_ws, size_t ws_size,
                              hipStream_t stream) {
  (void)in_sizes; (void)n_in; (void)d_ws; (void)ws_size; (void)out_size;
  // 16384 batch / 32 per block (2 tiles x 2 waves each) = 512 blocks
  // -> 2048 waves = 2 per SIMD.
  enc_kernel<<<dim3(512), dim3(256), 0, stream>>>(
      (const float*)d_in[0],
      (const float*)d_in[1],
      (const float*)d_in[2],
      (const float*)d_in[3],
      (const float*)d_in[4],
      (const float*)d_in[5],
      (const float*)d_in[6],
      (const float*)d_in[7],
      (const float*)d_in[8],
      (float*)d_out);
}

// Round 8
// 279.825 us; speedup vs baseline: 1.0351x; 1.0351x over previous
//
#include <hip/hip_runtime.h>

// Encoder: 2-layer LSTM (H=16 each), x [B=16384, T=100, I=18], FP32 in/out.
// R8: decoupled wave specialization. One 16-batch tile per 128-thread block
// (wave 0 = L1 producer, wave 1 = L2 consumer); 1024 blocks = 4 blocks/CU =
// 2 waves/SIMD. Handoff = packed relu(h1) B-frags through a 16-slot LDS ring
// with __syncthreads ONLY at 8-step group boundaries (13 barriers total vs
// R7's 100 -- R7's per-step barrier serialized the block and regressed).
// Producer writes group k then bars; consumer bars then reads group k-1;
// alternating 8-slot halves are disjoint, giving 8 steps of slack to absorb
// the ~57/43 producer/consumer imbalance. Each SIMD hosts 2 waves from
// DIFFERENT blocks (uncorrelated phases) that fill each other's latency gaps.
// Math identical to R6/R7 (absmax 9.77e-4): G^T = W @ H^T so packed
// (hi|lo<<16) h dwords ARE the next step's B-fragment; two-term bf16 splits
// on x/weights/states; gate math, biases, c-state in fp32.

typedef float f32x4 __attribute__((ext_vector_type(4)));
typedef __bf16 bf16x8 __attribute__((ext_vector_type(8)));
typedef unsigned int uint32x4 __attribute__((ext_vector_type(4)));

union FragU { bf16x8 v; unsigned short u[8]; unsigned int d[4]; uint32x4 q; };

#define MFMA16(A, B, C) __builtin_amdgcn_mfma_f32_16x16x32_bf16((A), (B), (C), 0, 0, 0)

static __device__ __forceinline__ unsigned short f2bf(float f) {  // RNE (weights)
  unsigned int u = __builtin_bit_cast(unsigned int, f);
  u = u + 0x7FFFu + ((u >> 16) & 1u);
  return (unsigned short)(u >> 16);
}
static __device__ __forceinline__ float bfbits2f(unsigned short h) {
  unsigned int u = ((unsigned int)h) << 16;
  return __builtin_bit_cast(float, u);
}
static __device__ __forceinline__ float sigm(float x) {
  return __builtin_amdgcn_rcpf(1.0f + __builtin_amdgcn_exp2f(x * -1.4426950408889634f));
}
static __device__ __forceinline__ float tanh_(float x) {
  return 1.0f - 2.0f * __builtin_amdgcn_rcpf(1.0f + __builtin_amdgcn_exp2f(x * 2.8853900817779268f));
}
// Trunc two-term split packed as (bf_hi | bf_lo<<16); hi+lo == v to 2^-16|v|.
static __device__ __forceinline__ unsigned int split_pack(float v) {
  unsigned int u = __builtin_bit_cast(unsigned int, v);
  float hf = __builtin_bit_cast(float, u & 0xFFFF0000u);
  unsigned int l = __builtin_bit_cast(unsigned int, v - hf);
  return (u >> 16) | (l & 0xFFFF0000u);
}
static __device__ __forceinline__ void cvt_pair(float f0, float f1,
                                                unsigned int& hd, unsigned int& ld) {
  unsigned int u0 = __builtin_bit_cast(unsigned int, f0);
  unsigned int u1 = __builtin_bit_cast(unsigned int, f1);
  unsigned int h0 = u0 & 0xFFFF0000u;
  unsigned int h1 = u1 & 0xFFFF0000u;
  hd = (u0 >> 16) | h1;
  unsigned int l0 = __builtin_bit_cast(unsigned int, f0 - __builtin_bit_cast(float, h0));
  unsigned int l1 = __builtin_bit_cast(unsigned int, f1 - __builtin_bit_cast(float, h1));
  ld = (l0 >> 16) | (l1 & 0xFFFF0000u);
}

struct RawX { float2 a, b2, c, d; };

#define NGRP 13  // groups of 8 steps: producer runs 104, consumer uses 100

__global__ __launch_bounds__(128, 2) void enc_kernel(
    const float* __restrict__ x,     // [16384,100,18]
    const float* __restrict__ Wih1,  // [64,18]
    const float* __restrict__ Whh1,  // [64,16]
    const float* __restrict__ bih1,  // [64]
    const float* __restrict__ bhh1,  // [64]
    const float* __restrict__ Wih2,  // [64,16]
    const float* __restrict__ Whh2,  // [64,16]
    const float* __restrict__ bih2,  // [64]
    const float* __restrict__ bhh2,  // [64]
    float* __restrict__ out)         // [16384,16]
{
  // 16-slot relu(h1) ring: slot t&15, 16B/lane -> 16 KB/block.
  __shared__ __align__(16) uint32x4 ring[16][64];

  const int wv   = threadIdx.x >> 6;  // 0 = L1 producer, 1 = L2 consumer
  const int lane = threadIdx.x & 63;
  const int b    = lane & 15;  // batch in tile (A m-row / B n-col / C col)
  const int g    = lane >> 4;  // k-group; C row-quad (units 4g..4g+3)
  const int b0   = (int)blockIdx.x * 16;

  if (wv == 0) {
    // ======================= L1 PRODUCER WAVE =======================
    FragU A1h[4], A1l[4], A2h[4], A2l[4];
    f32x4 bias1v[4];
#pragma unroll
    for (int tn = 0; tn < 4; ++tn) {  // 0=i 1=f 2=g 3=o
      const int row = tn * 16 + b;
#pragma unroll
      for (int j = 0; j < 8; ++j) {
        const int k = 8 * g + j;
        if (k < 18) {
          const float w = Wih1[row * 18 + k];
          A1h[tn].u[j] = f2bf(w);
          A1l[tn].u[j] = f2bf(w - bfbits2f(A1h[tn].u[j]));
        } else {
          A1h[tn].u[j] = 0;
          A1l[tn].u[j] = 0;
        }
        const float w2 = Whh1[row * 16 + (k >> 1)];  // hi/lo dup along K
        A2h[tn].u[j] = f2bf(w2);
        A2l[tn].u[j] = f2bf(w2 - bfbits2f(A2h[tn].u[j]));
      }
#pragma unroll
      for (int r = 0; r < 4; ++r) {
        const int u4 = tn * 16 + 4 * g + r;
        bias1v[tn][r] = bih1[u4] + bhh1[u4];
      }
    }

    // x: lane (b,g) covers x[b0+b][t][8g..8g+7]; g==3 is all zero-pad (k>=24).
    const float* const x0 = x + (size_t)(b0 + b) * 1800 + 8 * g;
    const int adv = (g == 3) ? 0 : 18;

    auto loadraw = [&](const float* p) -> RawX {
      RawX r;
      r.a = *(const float2*)p;
      if (g < 2) {
        r.b2 = *(const float2*)(p + 2);
        r.c  = *(const float2*)(p + 4);
        r.d  = *(const float2*)(p + 6);
      } else {
        r.b2 = r.c = r.d = make_float2(0.f, 0.f);
      }
      return r;
    };
    auto cvt = [&](const RawX& rw_, FragU& hi, FragU& lo) {
      cvt_pair(rw_.a.x,  rw_.a.y,  hi.d[0], lo.d[0]);
      cvt_pair(rw_.b2.x, rw_.b2.y, hi.d[1], lo.d[1]);
      cvt_pair(rw_.c.x,  rw_.c.y,  hi.d[2], lo.d[2]);
      cvt_pair(rw_.d.x,  rw_.d.y,  hi.d[3], lo.d[3]);
    };

    RawX rw0 = loadraw(x0);
    RawX rw1 = loadraw(x0 + adv);
    RawX rw  = loadraw(x0 + 2 * adv);
    const float* xq = x0 + 3 * adv;  // next load: t=3

    FragU hb;  hb.q = (uint32x4){0u, 0u, 0u, 0u};
    float c1[4] = {0.f, 0.f, 0.f, 0.f};

    FragU xch, xcl;
    cvt(rw0, xch, xcl);  // x(0)

    f32x4 ga[4];  // gate preacts for t=0 (hb = 0)
#pragma unroll
    for (int tn = 0; tn < 4; ++tn) {
      f32x4 acc = MFMA16(A1h[tn].v, xch.v, bias1v[tn]);
      acc = MFMA16(A1l[tn].v, xch.v, acc);
      acc = MFMA16(A1h[tn].v, xcl.v, acc);
      acc = MFMA16(A2h[tn].v, hb.v, acc);
      acc = MFMA16(A2l[tn].v, hb.v, acc);
      ga[tn] = acc;
    }
    cvt(rw1, xch, xcl);  // x(1) ready for the loop's first MFMAs

    int t = 0;
    for (int grp = 0; grp < NGRP; ++grp) {
#pragma unroll 2
      for (int i = 0; i < 8; ++i, ++t) {
        // steps t>=100 run harmlessly (finite garbage into never-read slots)
        FragU rb;
#pragma unroll
        for (int r = 0; r < 4; ++r) {
          const float iv = sigm(ga[0][r]);
          const float fv = sigm(ga[1][r]);
          const float gv = tanh_(ga[2][r]);
          const float ov = sigm(ga[3][r]);
          const float cc = fv * c1[r] + iv * gv;
          c1[r] = cc;
          const float h = ov * tanh_(cc);
          const unsigned int pk = split_pack(h);
          hb.d[r] = pk;
          rb.d[r] = (h > 0.f) ? pk : 0u;
        }
        ring[t & 15][lane] = rb.q;  // ds_write_b128

        // ga(t+1) from x(t+1) and h1(t)
#pragma unroll
        for (int tn = 0; tn < 4; ++tn) {
          f32x4 acc = MFMA16(A1h[tn].v, xch.v, bias1v[tn]);
          acc = MFMA16(A1l[tn].v, xch.v, acc);
          acc = MFMA16(A1h[tn].v, xcl.v, acc);
          acc = MFMA16(A2h[tn].v, hb.v, acc);
          acc = MFMA16(A2l[tn].v, hb.v, acc);
          ga[tn] = acc;
        }
        cvt(rw, xch, xcl);                  // x(t+2)
        rw = loadraw((t <= 96) ? xq : x0);  // x(t+3), uniform guard
        xq += adv;
      }
      __syncthreads();  // release group grp to the consumer
    }
  } else {
    // ======================= L2 CONSUMER WAVE =======================
    FragU A3h[4], A3l[4], A4h[4], A4l[4];
    f32x4 bias2v[4];
#pragma unroll
    for (int tn = 0; tn < 4; ++tn) {
      const int row = tn * 16 + b;
#pragma unroll
      for (int j = 0; j < 8; ++j) {
        const int kk = (8 * g + j) >> 1;  // hi/lo dup along K
        const float w3 = Wih2[row * 16 + kk];
        const float w4 = Whh2[row * 16 + kk];
        A3h[tn].u[j] = f2bf(w3); A3l[tn].u[j] = f2bf(w3 - bfbits2f(A3h[tn].u[j]));
        A4h[tn].u[j] = f2bf(w4); A4l[tn].u[j] = f2bf(w4 - bfbits2f(A4h[tn].u[j]));
      }
#pragma unroll
      for (int r = 0; r < 4; ++r) {
        const int u4 = tn * 16 + 4 * g + r;
        bias2v[tn][r] = bih2[u4] + bhh2[u4];
      }
    }

    FragU h2b;  h2b.q = (uint32x4){0u, 0u, 0u, 0u};
    float c2[4] = {0.f, 0.f, 0.f, 0.f};
    float h2v[4] = {0.f, 0.f, 0.f, 0.f};

    int t = 0;
    for (int grp = 0; grp < NGRP; ++grp) {
      __syncthreads();  // group grp now visible; slots (grp&1)*8.. are stable
      if (t < 100) {
#pragma unroll 2
        for (int i = 0; i < 8 && t < 100; ++i, ++t) {
          FragU rq;  rq.q = ring[t & 15][lane];

          // h2b-terms first: issue while the ds_read is in flight.
          f32x4 gb[4];
#pragma unroll
          for (int tn = 0; tn < 4; ++tn) {
            f32x4 acc = MFMA16(A4h[tn].v, h2b.v, bias2v[tn]);
            acc = MFMA16(A4l[tn].v, h2b.v, acc);
            acc = MFMA16(A3h[tn].v, rq.v, acc);
            acc = MFMA16(A3l[tn].v, rq.v, acc);
            gb[tn] = acc;
          }
#pragma unroll
          for (int r = 0; r < 4; ++r) {
            const float iv = sigm(gb[0][r]);
            const float fv = sigm(gb[1][r]);
            const float gv = tanh_(gb[2][r]);
            const float ov = sigm(gb[3][r]);
            const float cc = fv * c2[r] + iv * gv;
            c2[r] = cc;
            const float h = ov * tanh_(cc);
            h2v[r] = h;
            h2b.d[r] = split_pack(h);
          }
        }
      }
    }

    // output: relu(h2_last); lane (b,g) holds units 4g..4g+3 of batch b
    f32x4 o;
#pragma unroll
    for (int r = 0; r < 4; ++r) o[r] = fmaxf(h2v[r], 0.f);
    *(f32x4*)(out + (size_t)(b0 + b) * 16 + 4 * g) = o;
  }
}

extern "C" void kernel_launch(void* const* d_in, const int* in_sizes, int n_in,
                              void* d_out, int out_size, void* d_ws, size_t ws_size,
                              hipStream_t stream) {
  (void)in_sizes; (void)n_in; (void)d_ws; (void)ws_size; (void)out_size;
  // 16384 batch / 16 per block (1 tile, 2 waves) = 1024 blocks
  // -> 4 blocks/CU, 2 waves/SIMD, 16 KB LDS/block.
  enc_kernel<<<dim3(1024), dim3(128), 0, stream>>>(
      (const float*)d_in[0],
      (const float*)d_in[1],
      (const float*)d_in[2],
      (const float*)d_in[3],
      (const float*)d_in[4],
      (const float*)d_in[5],
      (const float*)d_in[6],
      (const float*)d_in[7],
      (const float*)d_in[8],
      (float*)d_out);
}